// Round 10
// baseline (115.463 us; speedup 1.0000x reference)
//
#include <hip/hip_runtime.h>
#include <math.h>

typedef float  f32x4   __attribute__((ext_vector_type(4)));
typedef __bf16 bf16x8  __attribute__((ext_vector_type(8)));
typedef unsigned short ushort_t;
typedef unsigned short ushort8 __attribute__((ext_vector_type(8)));

#define NTOK  4096   // H*W
#define CD    512    // C
#define DD    64     // D
#define BQ    256    // query tile (8 waves x 32 rows)
#define BK    64     // key tile
#define KSTR  72     // K/V LDS row stride (bf16 elems) - balanced for b128
#define PSTR  68     // P LDS row stride - row stride 136 dw = 8 mod 32
#define NROWS 16384  // B*NTOK
#define LOG2E 1.4426950408889634f

#define MFMA(a, b, c) __builtin_amdgcn_mfma_f32_16x16x32_bf16((a), (b), (c), 0, 0, 0)
#define EXP2(x) __builtin_amdgcn_exp2f(x)

static __device__ __forceinline__ ushort_t f2bf(float f) {
    union { __bf16 h; ushort_t u; } a; a.h = (__bf16)f; return a.u;
}
static __device__ __forceinline__ float bf2f(ushort_t h) {
    union { unsigned int u; float f; } a; a.u = ((unsigned int)h) << 16;
    return a.f;
}

// ---------------------------------------------------------------------------
// Kernel 0: weight prep. wqk_hi/lo[col][k] cols 0..127 (q=0-63 log2e-scaled,
// k=64-127), wv_t[d][k], woT[c][d] (plain bf16).
// ---------------------------------------------------------------------------
__global__ __launch_bounds__(256) void wprep_kernel(
    const float* __restrict__ Wq, const float* __restrict__ Wk,
    const float* __restrict__ Wv, const float* __restrict__ Wo,
    ushort_t* __restrict__ wqk_hi, ushort_t* __restrict__ wqk_lo,
    ushort_t* __restrict__ wv_t, ushort_t* __restrict__ woT)
{
    const int idx = blockIdx.x * 256 + threadIdx.x;   // 0 .. 131071
    if (idx < 192*512) {
        const int col = idx >> 9;                     // 0..191
        const int k   = idx & 511;
        const float* W = (col < 64) ? Wq : (col < 128 ? Wk : Wv);
        const int c = col & 63;
        float wv = W[(size_t)k*DD + c];
        if (col < 64) wv *= LOG2E;    // q scaled: scores in log2 domain
        const ushort_t h = f2bf(wv);
        if (col < 128) {
            wqk_hi[(size_t)col*CD + k] = h;
            wqk_lo[(size_t)col*CD + k] = f2bf(wv - bf2f(h));
        } else {
            wv_t[(size_t)(col - 128)*CD + k] = h;
        }
    } else {
        const int i = idx - 192*512;                  // 0 .. 32767
        const int c = i >> 6, d = i & 63;
        woT[i] = f2bf(Wo[(size_t)d*CD + c]);
    }
}

// ---------------------------------------------------------------------------
// Kernel 1: QKV projection as bf16-MFMA GEMM (unchanged from r7).
// ---------------------------------------------------------------------------
__global__ __launch_bounds__(256) void qkv_gemm(
    const float* __restrict__ x,
    const ushort_t* __restrict__ wqk_hi, const ushort_t* __restrict__ wqk_lo,
    const ushort_t* __restrict__ wv_t,
    const float* __restrict__ bq, const float* __restrict__ bk,
    const float* __restrict__ bv,
    ushort_t* __restrict__ qh, ushort_t* __restrict__ qlo,
    ushort_t* __restrict__ kh, ushort_t* __restrict__ klo,
    ushort_t* __restrict__ vT)
{
    __shared__ __align__(16) ushort_t xh_s [32*72];
    __shared__ __align__(16) ushort_t xl_s [32*72];
    __shared__ __align__(16) ushort_t whi_s[128*72];
    __shared__ __align__(16) ushort_t wlo_s[128*72];
    __shared__ __align__(16) ushort_t wv_s [64*72];
    __shared__ __align__(16) ushort_t vtile[64*40];

    const int tid  = threadIdx.x;
    const int w    = tid >> 6;
    const int lane = tid & 63;
    const int l15  = lane & 15;
    const int l4   = lane >> 4;
    const int r0   = blockIdx.x * 32;

    const int rf = w & 1;
    const int cg = w >> 1;

    f32x4 acc[6];
    #pragma unroll
    for (int j = 0; j < 6; ++j) acc[j] = (f32x4){0.f,0.f,0.f,0.f};

    const int xrow = tid >> 3, xk = (tid & 7) * 8;
    const int wcol = tid >> 1, wk = (tid & 1) * 32;
    const int vcol = tid >> 2, vk = (tid & 3) * 16;

    f32x4   px0, px1;
    ushort8 pwh[4], pwl[4], pwv[2];

    {
        const float* xp = &x[(size_t)(r0 + xrow)*CD + xk];
        px0 = *(const f32x4*)xp;  px1 = *(const f32x4*)(xp + 4);
        const ushort_t* hp = &wqk_hi[(size_t)wcol*CD + wk];
        const ushort_t* lp = &wqk_lo[(size_t)wcol*CD + wk];
        #pragma unroll
        for (int i = 0; i < 4; ++i) {
            pwh[i] = *(const ushort8*)(hp + 8*i);
            pwl[i] = *(const ushort8*)(lp + 8*i);
        }
        const ushort_t* vp = &wv_t[(size_t)vcol*CD + vk];
        pwv[0] = *(const ushort8*)vp;  pwv[1] = *(const ushort8*)(vp + 8);
    }

    for (int kt = 0; kt < 8; ++kt) {
        __syncthreads();
        {
            ushort8 hi8, lo8;
            #pragma unroll
            for (int i = 0; i < 8; ++i) {
                const float f = (i < 4) ? px0[i] : px1[i-4];
                const ushort_t h = f2bf(f);
                hi8[i] = h;
                lo8[i] = f2bf(f - bf2f(h));
            }
            *(ushort8*)&xh_s[xrow*72 + xk] = hi8;
            *(ushort8*)&xl_s[xrow*72 + xk] = lo8;
        }
        #pragma unroll
        for (int i = 0; i < 4; ++i) {
            *(ushort8*)&whi_s[wcol*72 + wk + 8*i] = pwh[i];
            *(ushort8*)&wlo_s[wcol*72 + wk + 8*i] = pwl[i];
        }
        *(ushort8*)&wv_s[vcol*72 + vk]     = pwv[0];
        *(ushort8*)&wv_s[vcol*72 + vk + 8] = pwv[1];

        if (kt + 1 < 8) {
            const int ko = (kt + 1) * 64;
            const float* xp = &x[(size_t)(r0 + xrow)*CD + ko + xk];
            px0 = *(const f32x4*)xp;  px1 = *(const f32x4*)(xp + 4);
            const ushort_t* hp = &wqk_hi[(size_t)wcol*CD + ko + wk];
            const ushort_t* lp = &wqk_lo[(size_t)wcol*CD + ko + wk];
            #pragma unroll
            for (int i = 0; i < 4; ++i) {
                pwh[i] = *(const ushort8*)(hp + 8*i);
                pwl[i] = *(const ushort8*)(lp + 8*i);
            }
            const ushort_t* vp = &wv_t[(size_t)vcol*CD + ko + vk];
            pwv[0] = *(const ushort8*)vp;  pwv[1] = *(const ushort8*)(vp + 8);
        }
        __syncthreads();

        #pragma unroll
        for (int k32 = 0; k32 < 2; ++k32) {
            const int ao = (rf*16 + l15)*72 + 8*l4 + 32*k32;
            bf16x8 ah = *(const bf16x8*)&xh_s[ao];
            bf16x8 al = *(const bf16x8*)&xl_s[ao];
            #pragma unroll
            for (int j = 0; j < 6; ++j) {
                const int cf = 6*cg + j;
                if (cf < 8) {
                    const int bo = (16*cf + l15)*72 + 8*l4 + 32*k32;
                    bf16x8 bh = *(const bf16x8*)&whi_s[bo];
                    bf16x8 bl = *(const bf16x8*)&wlo_s[bo];
                    acc[j] = MFMA(ah, bh, acc[j]);
                    acc[j] = MFMA(al, bh, acc[j]);
                    acc[j] = MFMA(ah, bl, acc[j]);
                } else {
                    const int bo = ((cf-8)*16 + l15)*72 + 8*l4 + 32*k32;
                    bf16x8 bv8 = *(const bf16x8*)&wv_s[bo];
                    acc[j] = MFMA(ah, bv8, acc[j]);
                    acc[j] = MFMA(al, bv8, acc[j]);
                }
            }
        }
    }

    #pragma unroll
    for (int j = 0; j < 6; ++j) {
        const int cf = 6*cg + j;
        const int col16 = cf*16 + l15;
        if (cf < 4) {
            const float bias = bq[col16] * LOG2E;
            #pragma unroll
            for (int r = 0; r < 4; ++r) {
                const size_t row = (size_t)(r0 + rf*16 + 4*l4 + r);
                const float qv = fmaxf(acc[j][r] + bias, 0.f);
                const ushort_t h = f2bf(qv);
                qh [row*DD + col16] = h;
                qlo[row*DD + col16] = f2bf(qv - bf2f(h));
            }
        } else if (cf < 8) {
            const int kc = col16 - 64;
            const float bias = bk[kc];
            #pragma unroll
            for (int r = 0; r < 4; ++r) {
                const size_t row = (size_t)(r0 + rf*16 + 4*l4 + r);
                const float kv = fmaxf(acc[j][r] + bias, 0.f);
                const ushort_t h = f2bf(kv);
                kh [row*DD + kc] = h;
                klo[row*DD + kc] = f2bf(kv - bf2f(h));
            }
        } else {
            const int d = col16 - 128;
            const float bias = bv[d];
            #pragma unroll
            for (int r = 0; r < 4; ++r)
                vtile[d*40 + rf*16 + 4*l4 + r] =
                    f2bf(fmaxf(acc[j][r] + bias, 0.f));
        }
    }
    __syncthreads();
    {
        const int d  = tid >> 2;
        const int j8 = (tid & 3) * 8;
        const int bb   = r0 / NTOK;
        const int tok0 = r0 % NTOK;
        ushort8 vv = *(const ushort8*)&vtile[d*40 + j8];
        *(ushort8*)&vT[((size_t)bb*DD + d)*NTOK + tok0 + j8] = vv;
    }
}

// ---------------------------------------------------------------------------
// Kernel 2: flash attention, BQ=256 (8 waves x 32 rows), split-K, NO-MAX
// exp2 softmax (scores log2-domain, bounded by data: relu'd q,k). K/V
// B-fragments read once per (nt,s) serve both row-frags -> half the LDS
// traffic. Row-sums deferred to one epilogue butterfly. Unnormalized
// partial (acc, l) per segment; oproj combines.
// ---------------------------------------------------------------------------
__global__ __launch_bounds__(512, 4) void attn_kernel(
    const ushort_t* __restrict__ qh, const ushort_t* __restrict__ qlo,
    const ushort_t* __restrict__ kh, const ushort_t* __restrict__ klo,
    const ushort_t* __restrict__ vT,
    float* __restrict__ o_part, float* __restrict__ l_part, int nseg)
{
    __shared__ __align__(16) ushort_t kh_s[BK*KSTR];
    __shared__ __align__(16) ushort_t kl_s[BK*KSTR];
    __shared__ __align__(16) ushort_t vt_s[DD*KSTR];   // [d][key]
    __shared__ __align__(16) ushort_t p_s [BQ*PSTR];   // wave-private rows

    const int tid  = threadIdx.x;
    const int w    = tid >> 6;     // 0..7
    const int lane = tid & 63;
    const int l15  = lane & 15;
    const int l4   = lane >> 4;
    const int b    = blockIdx.y;
    const int qb   = blockIdx.x;
    const int seg  = blockIdx.z;
    const int kv0  = seg * (NTOK / nseg);
    const int tiles = (NTOK / nseg) / BK;

    // Q fragments: 2 row-frags (u), 2 k-slices (s)
    bf16x8 qhf[2][2], qlf[2][2];
    #pragma unroll
    for (int u = 0; u < 2; ++u) {
        const size_t qrow = ((size_t)b*NTOK + (size_t)qb*BQ + 32*w + 16*u + l15)*DD;
        #pragma unroll
        for (int s = 0; s < 2; ++s) {
            qhf[u][s] = *(const bf16x8*)&qh [qrow + 8*l4 + 32*s];
            qlf[u][s] = *(const bf16x8*)&qlo[qrow + 8*l4 + 32*s];
        }
    }

    f32x4 acc[2][4];
    float l_run[2][4];
    #pragma unroll
    for (int u = 0; u < 2; ++u)
        #pragma unroll
        for (int nt = 0; nt < 4; ++nt) {
            acc[u][nt] = (f32x4){0.f,0.f,0.f,0.f};
            l_run[u][nt] = 0.f;   // [u][r] reuse index name
        }

    // staging: 512 thr, one b128 per array per thread
    const int skey = tid >> 3;          // 0..63
    const int sc   = (tid & 7) * 8;
    bf16x8 rgk, rgl, rgv;
    {
        const size_t kb = ((size_t)b*NTOK + kv0 + skey)*DD + sc;
        rgk = *(const bf16x8*)&kh [kb];
        rgl = *(const bf16x8*)&klo[kb];
        const size_t vb_ = ((size_t)b*DD + skey)*NTOK + kv0 + sc;
        rgv = *(const bf16x8*)&vT[vb_];
    }

    for (int t = 0; t < tiles; ++t) {
        __syncthreads();
        *(bf16x8*)&kh_s[skey*KSTR + sc] = rgk;
        *(bf16x8*)&kl_s[skey*KSTR + sc] = rgl;
        *(bf16x8*)&vt_s[skey*KSTR + sc] = rgv;
        __syncthreads();

        // ---- S (log2 domain) = Q K^T; B-frags shared across both u ----
        f32x4 sv[2][4];
        #pragma unroll
        for (int u = 0; u < 2; ++u)
            #pragma unroll
            for (int nt = 0; nt < 4; ++nt) sv[u][nt] = (f32x4){0.f,0.f,0.f,0.f};
        #pragma unroll
        for (int s = 0; s < 2; ++s)
            #pragma unroll
            for (int nt = 0; nt < 4; ++nt) {
                const int off = (16*nt + l15)*KSTR + 8*l4 + 32*s;
                bf16x8 khf = *(const bf16x8*)&kh_s[off];
                bf16x8 klf = *(const bf16x8*)&kl_s[off];
                #pragma unroll
                for (int u = 0; u < 2; ++u) {
                    sv[u][nt] = MFMA(qhf[u][s], khf, sv[u][nt]);
                    sv[u][nt] = MFMA(qhf[u][s], klf, sv[u][nt]);
                    sv[u][nt] = MFMA(qlf[u][s], khf, sv[u][nt]);
                }
            }

        // prefetch next tile (issued here: hides under softmax+PV)
        if (t + 1 < tiles) {
            const size_t kb = ((size_t)b*NTOK + kv0 + (t+1)*BK + skey)*DD + sc;
            rgk = *(const bf16x8*)&kh [kb];
            rgl = *(const bf16x8*)&klo[kb];
            const size_t vb_ = ((size_t)b*DD + skey)*NTOK + kv0 + (t+1)*BK + sc;
            rgv = *(const bf16x8*)&vT[vb_];
        }

        // ---- no-max softmax: P = exp2(S); deferred row-sum ----
        #pragma unroll
        for (int u = 0; u < 2; ++u)
            #pragma unroll
            for (int r = 0; r < 4; ++r) {
                float s0 = EXP2(sv[u][0][r]);
                float s1 = EXP2(sv[u][1][r]);
                float s2 = EXP2(sv[u][2][r]);
                float s3 = EXP2(sv[u][3][r]);
                sv[u][0][r] = s0; sv[u][1][r] = s1;
                sv[u][2][r] = s2; sv[u][3][r] = s3;
                l_run[u][r] += (s0 + s1) + (s2 + s3);
            }

        // ---- P -> LDS (bf16), wave-private rows ----
        #pragma unroll
        for (int u = 0; u < 2; ++u)
            #pragma unroll
            for (int nt = 0; nt < 4; ++nt)
                #pragma unroll
                for (int r = 0; r < 4; ++r)
                    p_s[(32*w + 16*u + 4*l4 + r)*PSTR + 16*nt + l15] =
                        f2bf(sv[u][nt][r]);

        // ---- PV: V-frags shared across both u ----
        bf16x8 paf[2][2];
        #pragma unroll
        for (int u = 0; u < 2; ++u)
            #pragma unroll
            for (int s = 0; s < 2; ++s)
                paf[u][s] = *(const bf16x8*)&p_s[(32*w + 16*u + l15)*PSTR + 8*l4 + 32*s];
        #pragma unroll
        for (int s = 0; s < 2; ++s)
            #pragma unroll
            for (int nt = 0; nt < 4; ++nt) {
                bf16x8 vf = *(const bf16x8*)&vt_s[(16*nt + l15)*KSTR + 8*l4 + 32*s];
                #pragma unroll
                for (int u = 0; u < 2; ++u)
                    acc[u][nt] = MFMA(paf[u][s], vf, acc[u][nt]);
            }
    }

    // epilogue: one butterfly row-sum, write unnormalized partials + l
    const size_t prow0 = (size_t)(seg*4 + b)*NTOK + (size_t)qb*BQ + 32*w;
    #pragma unroll
    for (int u = 0; u < 2; ++u)
        #pragma unroll
        for (int r = 0; r < 4; ++r) {
            float ls = l_run[u][r];
            ls += __shfl_xor(ls, 1);
            ls += __shfl_xor(ls, 2);
            ls += __shfl_xor(ls, 4);
            ls += __shfl_xor(ls, 8);
            const size_t row = prow0 + 16*u + 4*l4 + r;
            #pragma unroll
            for (int nt = 0; nt < 4; ++nt)
                o_part[row*DD + 16*nt + l15] = acc[u][nt][r];
            if (l15 == 0) l_part[row] = ls;
        }
}

// ---------------------------------------------------------------------------
// Kernel 3: output projection bf16-MFMA GEMM with fused split-K combine
// (unweighted sums now - no max tracking). 32-row tile, no LDS.
// ---------------------------------------------------------------------------
__global__ __launch_bounds__(256) void oproj_gemm(
    const float* __restrict__ o_part, const float* __restrict__ l_part,
    const ushort_t* __restrict__ woT, const float* __restrict__ bo,
    float* __restrict__ out, int nseg)
{
    const int tid  = threadIdx.x;
    const int w    = tid >> 6;
    const int lane = tid & 63;
    const int l15  = lane & 15;
    const int l4   = lane >> 4;
    const int r0   = blockIdx.x * 32;
    const int rf   = w & 1;
    const int cg   = w >> 1;

    const int row = r0 + rf*16 + l15;
    float lsum = 0.f;
    for (int s = 0; s < nseg; ++s)
        lsum += l_part[(size_t)s*NROWS + row];
    const float inv = 1.0f / lsum;

    f32x4 acc[16];
    #pragma unroll
    for (int j = 0; j < 16; ++j) acc[j] = (f32x4){0.f,0.f,0.f,0.f};

    #pragma unroll
    for (int ks = 0; ks < 2; ++ks) {
        const int k0 = 8*l4 + 32*ks;
        float ov[8] = {0.f,0.f,0.f,0.f,0.f,0.f,0.f,0.f};
        for (int s = 0; s < nseg; ++s) {
            const float* op = &o_part[((size_t)s*NROWS + row)*DD + k0];
            const f32x4 a0 = *(const f32x4*)op;
            const f32x4 a1 = *(const f32x4*)(op + 4);
            #pragma unroll
            for (int i = 0; i < 4; ++i) {
                ov[i]   += a0[i];
                ov[i+4] += a1[i];
            }
        }
        bf16x8 ah, al;
        #pragma unroll
        for (int i = 0; i < 8; ++i) {
            const float f = ov[i] * inv;
            ah[i] = (__bf16)f;
            al[i] = (__bf16)(f - (float)ah[i]);
        }
        #pragma unroll
        for (int j = 0; j < 16; ++j) {
            const int cf = cg*16 + j;
            const bf16x8 bfr = *(const bf16x8*)&woT[(size_t)(16*cf + l15)*DD + k0];
            acc[j] = MFMA(ah, bfr, acc[j]);
            acc[j] = MFMA(al, bfr, acc[j]);
        }
    }

    #pragma unroll
    for (int j = 0; j < 16; ++j) {
        const int col  = (cg*16 + j)*16 + l15;
        const float bias = bo[col];
        #pragma unroll
        for (int r = 0; r < 4; ++r)
            out[(size_t)(r0 + rf*16 + 4*l4 + r)*CD + col] =
                fmaxf(acc[j][r] + bias, 0.f);
    }
}

// ---------------------------------------------------------------------------
extern "C" void kernel_launch(void* const* d_in, const int* in_sizes, int n_in,
                              void* d_out, int out_size, void* d_ws, size_t ws_size,
                              hipStream_t stream) {
    const float* x  = (const float*)d_in[0];
    const float* Wq = (const float*)d_in[1];
    const float* bq = (const float*)d_in[2];
    const float* Wk = (const float*)d_in[3];
    const float* bk = (const float*)d_in[4];
    const float* Wv = (const float*)d_in[5];
    const float* bv = (const float*)d_in[6];
    const float* Wo = (const float*)d_in[7];
    const float* bo = (const float*)d_in[8];
    float* out = (float*)d_out;

    ushort_t* u = (ushort_t*)d_ws;
    const size_t SEG = (size_t)NROWS * DD;  // 1048576 elems
    ushort_t* qh  = u;
    ushort_t* qlo = u + SEG;
    ushort_t* kh  = u + 2*SEG;
    ushort_t* klo = u + 3*SEG;
    ushort_t* vT  = u + 4*SEG;

    ushort_t* wqk_hi = u + 5*SEG;           // 128*512
    ushort_t* wqk_lo = wqk_hi + 128*512;
    ushort_t* wv_t   = wqk_lo + 128*512;    // 64*512
    ushort_t* woT    = wv_t + 64*512;       // 512*64
    float*    o_part = (float*)(woT + 512*64);

    const size_t base_b  = (5*SEG + 320*512 + 512*64) * sizeof(ushort_t);
    const size_t per_seg = (size_t)NROWS*DD*4 + (size_t)NROWS*4;  // 4MB+64KB
    int nseg = 1;
    if      (ws_size >= base_b + 8*per_seg) nseg = 8;
    else if (ws_size >= base_b + 4*per_seg) nseg = 4;
    else if (ws_size >= base_b + 2*per_seg) nseg = 2;
    float* l_part = o_part + (size_t)nseg*NROWS*DD;

    wprep_kernel<<<512, 256, 0, stream>>>(Wq, Wk, Wv, Wo,
                                          wqk_hi, wqk_lo, wv_t, woT);
    qkv_gemm<<<NROWS/32, 256, 0, stream>>>(x, wqk_hi, wqk_lo, wv_t,
                                           bq, bk, bv, qh, qlo, kh, klo, vT);
    attn_kernel<<<dim3(NTOK/BQ, 4, nseg), 512, 0, stream>>>(
        qh, qlo, kh, klo, vT, o_part, l_part, nseg);
    oproj_gemm<<<NROWS/32, 256, 0, stream>>>(o_part, l_part, woT,
                                             bo, out, nseg);
}

// Round 11
// 109.022 us; speedup vs baseline: 1.0591x; 1.0591x over previous
//
#include <hip/hip_runtime.h>
#include <math.h>

typedef float  f32x4   __attribute__((ext_vector_type(4)));
typedef __bf16 bf16x8  __attribute__((ext_vector_type(8)));
typedef unsigned short ushort_t;
typedef unsigned short ushort8 __attribute__((ext_vector_type(8)));

#define NTOK  4096   // H*W
#define CD    512    // C
#define DD    64     // D
#define BQ    256    // query tile (8 waves x 32 rows)
#define BK    64     // key tile
#define KSTR  72     // K/V LDS row stride (bf16 elems)
#define PSTR  68     // P LDS row stride
#define NROWS 16384  // B*NTOK
#define LOG2E 1.4426950408889634f

#define MFMA(a, b, c) __builtin_amdgcn_mfma_f32_16x16x32_bf16((a), (b), (c), 0, 0, 0)
#define EXP2(x) __builtin_amdgcn_exp2f(x)

static __device__ __forceinline__ ushort_t f2bf(float f) {
    union { __bf16 h; ushort_t u; } a; a.h = (__bf16)f; return a.u;
}
static __device__ __forceinline__ float bf2f(ushort_t h) {
    union { unsigned int u; float f; } a; a.u = ((unsigned int)h) << 16;
    return a.f;
}

// ---------------------------------------------------------------------------
// Kernel 0: weight prep (unchanged from r10).
// ---------------------------------------------------------------------------
__global__ __launch_bounds__(256) void wprep_kernel(
    const float* __restrict__ Wq, const float* __restrict__ Wk,
    const float* __restrict__ Wv, const float* __restrict__ Wo,
    ushort_t* __restrict__ wqk_hi, ushort_t* __restrict__ wqk_lo,
    ushort_t* __restrict__ wv_t, ushort_t* __restrict__ woT)
{
    const int idx = blockIdx.x * 256 + threadIdx.x;   // 0 .. 131071
    if (idx < 192*512) {
        const int col = idx >> 9;                     // 0..191
        const int k   = idx & 511;
        const float* W = (col < 64) ? Wq : (col < 128 ? Wk : Wv);
        const int c = col & 63;
        float wv = W[(size_t)k*DD + c];
        if (col < 64) wv *= LOG2E;    // q scaled: scores in log2 domain
        const ushort_t h = f2bf(wv);
        if (col < 128) {
            wqk_hi[(size_t)col*CD + k] = h;
            wqk_lo[(size_t)col*CD + k] = f2bf(wv - bf2f(h));
        } else {
            wv_t[(size_t)(col - 128)*CD + k] = h;
        }
    } else {
        const int i = idx - 192*512;                  // 0 .. 32767
        const int c = i >> 6, d = i & 63;
        woT[i] = f2bf(Wo[(size_t)d*CD + c]);
    }
}

// ---------------------------------------------------------------------------
// Kernel 1: QKV projection as bf16-MFMA GEMM (unchanged from r7).
// ---------------------------------------------------------------------------
__global__ __launch_bounds__(256) void qkv_gemm(
    const float* __restrict__ x,
    const ushort_t* __restrict__ wqk_hi, const ushort_t* __restrict__ wqk_lo,
    const ushort_t* __restrict__ wv_t,
    const float* __restrict__ bq, const float* __restrict__ bk,
    const float* __restrict__ bv,
    ushort_t* __restrict__ qh, ushort_t* __restrict__ qlo,
    ushort_t* __restrict__ kh, ushort_t* __restrict__ klo,
    ushort_t* __restrict__ vT)
{
    __shared__ __align__(16) ushort_t xh_s [32*72];
    __shared__ __align__(16) ushort_t xl_s [32*72];
    __shared__ __align__(16) ushort_t whi_s[128*72];
    __shared__ __align__(16) ushort_t wlo_s[128*72];
    __shared__ __align__(16) ushort_t wv_s [64*72];
    __shared__ __align__(16) ushort_t vtile[64*40];

    const int tid  = threadIdx.x;
    const int w    = tid >> 6;
    const int lane = tid & 63;
    const int l15  = lane & 15;
    const int l4   = lane >> 4;
    const int r0   = blockIdx.x * 32;

    const int rf = w & 1;
    const int cg = w >> 1;

    f32x4 acc[6];
    #pragma unroll
    for (int j = 0; j < 6; ++j) acc[j] = (f32x4){0.f,0.f,0.f,0.f};

    const int xrow = tid >> 3, xk = (tid & 7) * 8;
    const int wcol = tid >> 1, wk = (tid & 1) * 32;
    const int vcol = tid >> 2, vk = (tid & 3) * 16;

    f32x4   px0, px1;
    ushort8 pwh[4], pwl[4], pwv[2];

    {
        const float* xp = &x[(size_t)(r0 + xrow)*CD + xk];
        px0 = *(const f32x4*)xp;  px1 = *(const f32x4*)(xp + 4);
        const ushort_t* hp = &wqk_hi[(size_t)wcol*CD + wk];
        const ushort_t* lp = &wqk_lo[(size_t)wcol*CD + wk];
        #pragma unroll
        for (int i = 0; i < 4; ++i) {
            pwh[i] = *(const ushort8*)(hp + 8*i);
            pwl[i] = *(const ushort8*)(lp + 8*i);
        }
        const ushort_t* vp = &wv_t[(size_t)vcol*CD + vk];
        pwv[0] = *(const ushort8*)vp;  pwv[1] = *(const ushort8*)(vp + 8);
    }

    for (int kt = 0; kt < 8; ++kt) {
        __syncthreads();
        {
            ushort8 hi8, lo8;
            #pragma unroll
            for (int i = 0; i < 8; ++i) {
                const float f = (i < 4) ? px0[i] : px1[i-4];
                const ushort_t h = f2bf(f);
                hi8[i] = h;
                lo8[i] = f2bf(f - bf2f(h));
            }
            *(ushort8*)&xh_s[xrow*72 + xk] = hi8;
            *(ushort8*)&xl_s[xrow*72 + xk] = lo8;
        }
        #pragma unroll
        for (int i = 0; i < 4; ++i) {
            *(ushort8*)&whi_s[wcol*72 + wk + 8*i] = pwh[i];
            *(ushort8*)&wlo_s[wcol*72 + wk + 8*i] = pwl[i];
        }
        *(ushort8*)&wv_s[vcol*72 + vk]     = pwv[0];
        *(ushort8*)&wv_s[vcol*72 + vk + 8] = pwv[1];

        if (kt + 1 < 8) {
            const int ko = (kt + 1) * 64;
            const float* xp = &x[(size_t)(r0 + xrow)*CD + ko + xk];
            px0 = *(const f32x4*)xp;  px1 = *(const f32x4*)(xp + 4);
            const ushort_t* hp = &wqk_hi[(size_t)wcol*CD + ko + wk];
            const ushort_t* lp = &wqk_lo[(size_t)wcol*CD + ko + wk];
            #pragma unroll
            for (int i = 0; i < 4; ++i) {
                pwh[i] = *(const ushort8*)(hp + 8*i);
                pwl[i] = *(const ushort8*)(lp + 8*i);
            }
            const ushort_t* vp = &wv_t[(size_t)vcol*CD + ko + vk];
            pwv[0] = *(const ushort8*)vp;  pwv[1] = *(const ushort8*)(vp + 8);
        }
        __syncthreads();

        #pragma unroll
        for (int k32 = 0; k32 < 2; ++k32) {
            const int ao = (rf*16 + l15)*72 + 8*l4 + 32*k32;
            bf16x8 ah = *(const bf16x8*)&xh_s[ao];
            bf16x8 al = *(const bf16x8*)&xl_s[ao];
            #pragma unroll
            for (int j = 0; j < 6; ++j) {
                const int cf = 6*cg + j;
                if (cf < 8) {
                    const int bo = (16*cf + l15)*72 + 8*l4 + 32*k32;
                    bf16x8 bh = *(const bf16x8*)&whi_s[bo];
                    bf16x8 bl = *(const bf16x8*)&wlo_s[bo];
                    acc[j] = MFMA(ah, bh, acc[j]);
                    acc[j] = MFMA(al, bh, acc[j]);
                    acc[j] = MFMA(ah, bl, acc[j]);
                } else {
                    const int bo = ((cf-8)*16 + l15)*72 + 8*l4 + 32*k32;
                    bf16x8 bv8 = *(const bf16x8*)&wv_s[bo];
                    acc[j] = MFMA(ah, bv8, acc[j]);
                    acc[j] = MFMA(al, bv8, acc[j]);
                }
            }
        }
    }

    #pragma unroll
    for (int j = 0; j < 6; ++j) {
        const int cf = 6*cg + j;
        const int col16 = cf*16 + l15;
        if (cf < 4) {
            const float bias = bq[col16] * LOG2E;
            #pragma unroll
            for (int r = 0; r < 4; ++r) {
                const size_t row = (size_t)(r0 + rf*16 + 4*l4 + r);
                const float qv = fmaxf(acc[j][r] + bias, 0.f);
                const ushort_t h = f2bf(qv);
                qh [row*DD + col16] = h;
                qlo[row*DD + col16] = f2bf(qv - bf2f(h));
            }
        } else if (cf < 8) {
            const int kc = col16 - 64;
            const float bias = bk[kc];
            #pragma unroll
            for (int r = 0; r < 4; ++r) {
                const size_t row = (size_t)(r0 + rf*16 + 4*l4 + r);
                const float kv = fmaxf(acc[j][r] + bias, 0.f);
                const ushort_t h = f2bf(kv);
                kh [row*DD + kc] = h;
                klo[row*DD + kc] = f2bf(kv - bf2f(h));
            }
        } else {
            const int d = col16 - 128;
            const float bias = bv[d];
            #pragma unroll
            for (int r = 0; r < 4; ++r)
                vtile[d*40 + rf*16 + 4*l4 + r] =
                    f2bf(fmaxf(acc[j][r] + bias, 0.f));
        }
    }
    __syncthreads();
    {
        const int d  = tid >> 2;
        const int j8 = (tid & 3) * 8;
        const int bb   = r0 / NTOK;
        const int tok0 = r0 % NTOK;
        ushort8 vv = *(const ushort8*)&vtile[d*40 + j8];
        *(ushort8*)&vT[((size_t)bb*DD + d)*NTOK + tok0 + j8] = vv;
    }
}

// ---------------------------------------------------------------------------
// Kernel 2: flash attention, BQ=256 (8 waves x 32 rows), split-K, no-max
// exp2 softmax. CHANGES vs r10: (1) 1-D grid with seg = bid % nseg so at
// nseg=8 each K/V segment pins to one XCD (dispatch round-robins id%8) ->
// K/V prefetches hit that XCD's L2; (2) next-tile prefetch issued right
// after the stage-write (a FULL compute phase of cover, not just PV).
// ---------------------------------------------------------------------------
__global__ __launch_bounds__(512, 4) void attn_kernel(
    const ushort_t* __restrict__ qh, const ushort_t* __restrict__ qlo,
    const ushort_t* __restrict__ kh, const ushort_t* __restrict__ klo,
    const ushort_t* __restrict__ vT,
    float* __restrict__ o_part, float* __restrict__ l_part, int nseg)
{
    __shared__ __align__(16) ushort_t kh_s[BK*KSTR];
    __shared__ __align__(16) ushort_t kl_s[BK*KSTR];
    __shared__ __align__(16) ushort_t vt_s[DD*KSTR];   // [d][key]
    __shared__ __align__(16) ushort_t p_s [BQ*PSTR];   // wave-private rows

    const int tid  = threadIdx.x;
    const int w    = tid >> 6;     // 0..7
    const int lane = tid & 63;
    const int l15  = lane & 15;
    const int l4   = lane >> 4;

    // XCD-aware decode: seg == bid % nseg -> at nseg==8 each segment's 64
    // blocks land on one XCD (its K/V chunk becomes L2-resident there).
    const int p    = blockIdx.x;
    const int seg  = p % nseg;
    const int rest = p / nseg;
    const int qb   = rest & (NTOK/BQ - 1);   // 16 q-tiles
    const int b    = rest / (NTOK/BQ);
    const int kv0  = seg * (NTOK / nseg);
    const int tiles = (NTOK / nseg) / BK;

    // Q fragments: 2 row-frags (u), 2 k-slices (s)
    bf16x8 qhf[2][2], qlf[2][2];
    #pragma unroll
    for (int u = 0; u < 2; ++u) {
        const size_t qrow = ((size_t)b*NTOK + (size_t)qb*BQ + 32*w + 16*u + l15)*DD;
        #pragma unroll
        for (int s = 0; s < 2; ++s) {
            qhf[u][s] = *(const bf16x8*)&qh [qrow + 8*l4 + 32*s];
            qlf[u][s] = *(const bf16x8*)&qlo[qrow + 8*l4 + 32*s];
        }
    }

    f32x4 acc[2][4];
    float l_run[2][4];
    #pragma unroll
    for (int u = 0; u < 2; ++u)
        #pragma unroll
        for (int nt = 0; nt < 4; ++nt) {
            acc[u][nt] = (f32x4){0.f,0.f,0.f,0.f};
            l_run[u][nt] = 0.f;
        }

    // staging: 512 thr, one b128 per array per thread
    const int skey = tid >> 3;          // 0..63
    const int sc   = (tid & 7) * 8;
    bf16x8 rgk, rgl, rgv;
    {
        const size_t kb = ((size_t)b*NTOK + kv0 + skey)*DD + sc;
        rgk = *(const bf16x8*)&kh [kb];
        rgl = *(const bf16x8*)&klo[kb];
        const size_t vb_ = ((size_t)b*DD + skey)*NTOK + kv0 + sc;
        rgv = *(const bf16x8*)&vT[vb_];
    }

    for (int t = 0; t < tiles; ++t) {
        __syncthreads();
        *(bf16x8*)&kh_s[skey*KSTR + sc] = rgk;
        *(bf16x8*)&kl_s[skey*KSTR + sc] = rgl;
        *(bf16x8*)&vt_s[skey*KSTR + sc] = rgv;
        // prefetch t+1 NOW: issue-to-use gap spans the whole compute phase
        if (t + 1 < tiles) {
            const size_t kb = ((size_t)b*NTOK + kv0 + (t+1)*BK + skey)*DD + sc;
            rgk = *(const bf16x8*)&kh [kb];
            rgl = *(const bf16x8*)&klo[kb];
            const size_t vb_ = ((size_t)b*DD + skey)*NTOK + kv0 + (t+1)*BK + sc;
            rgv = *(const bf16x8*)&vT[vb_];
        }
        __syncthreads();

        // ---- S (log2 domain) = Q K^T; B-frags shared across both u ----
        f32x4 sv[2][4];
        #pragma unroll
        for (int u = 0; u < 2; ++u)
            #pragma unroll
            for (int nt = 0; nt < 4; ++nt) sv[u][nt] = (f32x4){0.f,0.f,0.f,0.f};
        #pragma unroll
        for (int s = 0; s < 2; ++s)
            #pragma unroll
            for (int nt = 0; nt < 4; ++nt) {
                const int off = (16*nt + l15)*KSTR + 8*l4 + 32*s;
                bf16x8 khf = *(const bf16x8*)&kh_s[off];
                bf16x8 klf = *(const bf16x8*)&kl_s[off];
                #pragma unroll
                for (int u = 0; u < 2; ++u) {
                    sv[u][nt] = MFMA(qhf[u][s], khf, sv[u][nt]);
                    sv[u][nt] = MFMA(qhf[u][s], klf, sv[u][nt]);
                    sv[u][nt] = MFMA(qlf[u][s], khf, sv[u][nt]);
                }
            }

        // ---- no-max softmax: P = exp2(S); deferred row-sum ----
        #pragma unroll
        for (int u = 0; u < 2; ++u)
            #pragma unroll
            for (int r = 0; r < 4; ++r) {
                float s0 = EXP2(sv[u][0][r]);
                float s1 = EXP2(sv[u][1][r]);
                float s2 = EXP2(sv[u][2][r]);
                float s3 = EXP2(sv[u][3][r]);
                sv[u][0][r] = s0; sv[u][1][r] = s1;
                sv[u][2][r] = s2; sv[u][3][r] = s3;
                l_run[u][r] += (s0 + s1) + (s2 + s3);
            }

        // ---- P -> LDS (bf16), wave-private rows ----
        #pragma unroll
        for (int u = 0; u < 2; ++u)
            #pragma unroll
            for (int nt = 0; nt < 4; ++nt)
                #pragma unroll
                for (int r = 0; r < 4; ++r)
                    p_s[(32*w + 16*u + 4*l4 + r)*PSTR + 16*nt + l15] =
                        f2bf(sv[u][nt][r]);

        // ---- PV: V-frags shared across both u ----
        bf16x8 paf[2][2];
        #pragma unroll
        for (int u = 0; u < 2; ++u)
            #pragma unroll
            for (int s = 0; s < 2; ++s)
                paf[u][s] = *(const bf16x8*)&p_s[(32*w + 16*u + l15)*PSTR + 8*l4 + 32*s];
        #pragma unroll
        for (int s = 0; s < 2; ++s)
            #pragma unroll
            for (int nt = 0; nt < 4; ++nt) {
                bf16x8 vf = *(const bf16x8*)&vt_s[(16*nt + l15)*KSTR + 8*l4 + 32*s];
                #pragma unroll
                for (int u = 0; u < 2; ++u)
                    acc[u][nt] = MFMA(paf[u][s], vf, acc[u][nt]);
            }
    }

    // epilogue: one butterfly row-sum, write unnormalized partials + l
    const size_t prow0 = (size_t)(seg*4 + b)*NTOK + (size_t)qb*BQ + 32*w;
    #pragma unroll
    for (int u = 0; u < 2; ++u)
        #pragma unroll
        for (int r = 0; r < 4; ++r) {
            float ls = l_run[u][r];
            ls += __shfl_xor(ls, 1);
            ls += __shfl_xor(ls, 2);
            ls += __shfl_xor(ls, 4);
            ls += __shfl_xor(ls, 8);
            const size_t row = prow0 + 16*u + 4*l4 + r;
            #pragma unroll
            for (int nt = 0; nt < 4; ++nt)
                o_part[row*DD + 16*nt + l15] = acc[u][nt][r];
            if (l15 == 0) l_part[row] = ls;
        }
}

// ---------------------------------------------------------------------------
// Kernel 3: output projection bf16-MFMA GEMM with fused split-K combine
// (unchanged from r10).
// ---------------------------------------------------------------------------
__global__ __launch_bounds__(256) void oproj_gemm(
    const float* __restrict__ o_part, const float* __restrict__ l_part,
    const ushort_t* __restrict__ woT, const float* __restrict__ bo,
    float* __restrict__ out, int nseg)
{
    const int tid  = threadIdx.x;
    const int w    = tid >> 6;
    const int lane = tid & 63;
    const int l15  = lane & 15;
    const int l4   = lane >> 4;
    const int r0   = blockIdx.x * 32;
    const int rf   = w & 1;
    const int cg   = w >> 1;

    const int row = r0 + rf*16 + l15;
    float lsum = 0.f;
    for (int s = 0; s < nseg; ++s)
        lsum += l_part[(size_t)s*NROWS + row];
    const float inv = 1.0f / lsum;

    f32x4 acc[16];
    #pragma unroll
    for (int j = 0; j < 16; ++j) acc[j] = (f32x4){0.f,0.f,0.f,0.f};

    #pragma unroll
    for (int ks = 0; ks < 2; ++ks) {
        const int k0 = 8*l4 + 32*ks;
        float ov[8] = {0.f,0.f,0.f,0.f,0.f,0.f,0.f,0.f};
        for (int s = 0; s < nseg; ++s) {
            const float* op = &o_part[((size_t)s*NROWS + row)*DD + k0];
            const f32x4 a0 = *(const f32x4*)op;
            const f32x4 a1 = *(const f32x4*)(op + 4);
            #pragma unroll
            for (int i = 0; i < 4; ++i) {
                ov[i]   += a0[i];
                ov[i+4] += a1[i];
            }
        }
        bf16x8 ah, al;
        #pragma unroll
        for (int i = 0; i < 8; ++i) {
            const float f = ov[i] * inv;
            ah[i] = (__bf16)f;
            al[i] = (__bf16)(f - (float)ah[i]);
        }
        #pragma unroll
        for (int j = 0; j < 16; ++j) {
            const int cf = cg*16 + j;
            const bf16x8 bfr = *(const bf16x8*)&woT[(size_t)(16*cf + l15)*DD + k0];
            acc[j] = MFMA(ah, bfr, acc[j]);
            acc[j] = MFMA(al, bfr, acc[j]);
        }
    }

    #pragma unroll
    for (int j = 0; j < 16; ++j) {
        const int col  = (cg*16 + j)*16 + l15;
        const float bias = bo[col];
        #pragma unroll
        for (int r = 0; r < 4; ++r)
            out[(size_t)(r0 + rf*16 + 4*l4 + r)*CD + col] =
                fmaxf(acc[j][r] + bias, 0.f);
    }
}

// ---------------------------------------------------------------------------
extern "C" void kernel_launch(void* const* d_in, const int* in_sizes, int n_in,
                              void* d_out, int out_size, void* d_ws, size_t ws_size,
                              hipStream_t stream) {
    const float* x  = (const float*)d_in[0];
    const float* Wq = (const float*)d_in[1];
    const float* bq = (const float*)d_in[2];
    const float* Wk = (const float*)d_in[3];
    const float* bk = (const float*)d_in[4];
    const float* Wv = (const float*)d_in[5];
    const float* bv = (const float*)d_in[6];
    const float* Wo = (const float*)d_in[7];
    const float* bo = (const float*)d_in[8];
    float* out = (float*)d_out;

    ushort_t* u = (ushort_t*)d_ws;
    const size_t SEG = (size_t)NROWS * DD;  // 1048576 elems
    ushort_t* qh  = u;
    ushort_t* qlo = u + SEG;
    ushort_t* kh  = u + 2*SEG;
    ushort_t* klo = u + 3*SEG;
    ushort_t* vT  = u + 4*SEG;

    ushort_t* wqk_hi = u + 5*SEG;           // 128*512
    ushort_t* wqk_lo = wqk_hi + 128*512;
    ushort_t* wv_t   = wqk_lo + 128*512;    // 64*512
    ushort_t* woT    = wv_t + 64*512;       // 512*64
    float*    o_part = (float*)(woT + 512*64);

    const size_t base_b  = (5*SEG + 320*512 + 512*64) * sizeof(ushort_t);
    const size_t per_seg = (size_t)NROWS*DD*4 + (size_t)NROWS*4;  // 4MB+64KB
    int nseg = 1;
    if      (ws_size >= base_b + 8*per_seg) nseg = 8;
    else if (ws_size >= base_b + 4*per_seg) nseg = 4;
    else if (ws_size >= base_b + 2*per_seg) nseg = 2;
    float* l_part = o_part + (size_t)nseg*NROWS*DD;

    wprep_kernel<<<512, 256, 0, stream>>>(Wq, Wk, Wv, Wo,
                                          wqk_hi, wqk_lo, wv_t, woT);
    qkv_gemm<<<NROWS/32, 256, 0, stream>>>(x, wqk_hi, wqk_lo, wv_t,
                                           bq, bk, bv, qh, qlo, kh, klo, vT);
    attn_kernel<<<(NTOK/BQ) * 4 * nseg, 512, 0, stream>>>(
        qh, qlo, kh, klo, vT, o_part, l_part, nseg);
    oproj_gemm<<<NROWS/32, 256, 0, stream>>>(o_part, l_part, woT,
                                             bo, out, nseg);
}

// Round 12
// 75.918 us; speedup vs baseline: 1.5209x; 1.4360x over previous
//
#include <hip/hip_runtime.h>
#include <math.h>

typedef float    f32x4  __attribute__((ext_vector_type(4)));
typedef __bf16   bf16x8 __attribute__((ext_vector_type(8)));
typedef _Float16 half8  __attribute__((ext_vector_type(8)));
typedef unsigned short ushort_t;
typedef unsigned short ushort8 __attribute__((ext_vector_type(8)));

#define NTOK  4096   // H*W
#define CD    512    // C
#define DD    64     // D
#define BQ    256    // query tile (8 waves x 32 rows)
#define BK    64     // key tile
#define KSTR  72     // K/V LDS row stride (elems)
#define PSTR  68     // P LDS row stride
#define NROWS 16384  // B*NTOK
#define LOG2E 1.4426950408889634f

#define MFMAH(a, b, c) __builtin_amdgcn_mfma_f32_16x16x32_f16((a), (b), (c), 0, 0, 0)
#define MFMAB(a, b, c) __builtin_amdgcn_mfma_f32_16x16x32_bf16((a), (b), (c), 0, 0, 0)
#define EXP2(x) __builtin_amdgcn_exp2f(x)

static __device__ __forceinline__ ushort_t f2h(float f) {
    union { _Float16 h; ushort_t u; } a; a.h = (_Float16)f; return a.u;
}
static __device__ __forceinline__ ushort_t f2bf(float f) {
    union { __bf16 h; ushort_t u; } a; a.h = (__bf16)f; return a.u;
}

// ---------------------------------------------------------------------------
// Kernel 0: weight prep. ALL fp16 now: wqk[col][k] cols 0..127 (q=0-63
// log2e-scaled, k=64-127), wv_t[d][k], woT[c][d]. Single arrays (no hi/lo).
// ---------------------------------------------------------------------------
__global__ __launch_bounds__(256) void wprep_kernel(
    const float* __restrict__ Wq, const float* __restrict__ Wk,
    const float* __restrict__ Wv, const float* __restrict__ Wo,
    ushort_t* __restrict__ wqk, ushort_t* __restrict__ wv_t,
    ushort_t* __restrict__ woT)
{
    const int idx = blockIdx.x * 256 + threadIdx.x;   // 0 .. 131071
    if (idx < 192*512) {
        const int col = idx >> 9;                     // 0..191
        const int k   = idx & 511;
        const float* W = (col < 64) ? Wq : (col < 128 ? Wk : Wv);
        const int c = col & 63;
        float wv = W[(size_t)k*DD + c];
        if (col < 64) wv *= LOG2E;    // q scaled: scores in log2 domain
        if (col < 128) wqk[(size_t)col*CD + k] = f2h(wv);
        else           wv_t[(size_t)(col - 128)*CD + k] = f2h(wv);
    } else {
        const int i = idx - 192*512;                  // 0 .. 32767
        const int c = i >> 6, d = i & 63;
        woT[i] = f2h(Wo[(size_t)d*CD + c]);
    }
}

// ---------------------------------------------------------------------------
// Kernel 1: QKV projection, fp16 MFMA (single per product). Outputs q,k fp16
// row-major; v -> bf16, transposed vT[b][d][tok] (PV stays bf16 for range).
// ---------------------------------------------------------------------------
__global__ __launch_bounds__(256) void qkv_gemm(
    const float* __restrict__ x,
    const ushort_t* __restrict__ wqk, const ushort_t* __restrict__ wv_t,
    const float* __restrict__ bq, const float* __restrict__ bk,
    const float* __restrict__ bv,
    ushort_t* __restrict__ qf, ushort_t* __restrict__ kf,
    ushort_t* __restrict__ vT)
{
    __shared__ __align__(16) ushort_t xs_s [32*72];    // x fp16
    __shared__ __align__(16) ushort_t wqk_s[128*72];   // fp16
    __shared__ __align__(16) ushort_t wv_s [64*72];    // fp16
    __shared__ __align__(16) ushort_t vtile[64*40];    // bf16 [d][tok]

    const int tid  = threadIdx.x;
    const int w    = tid >> 6;
    const int lane = tid & 63;
    const int l15  = lane & 15;
    const int l4   = lane >> 4;
    const int r0   = blockIdx.x * 32;

    const int rf = w & 1;
    const int cg = w >> 1;

    f32x4 acc[6];
    #pragma unroll
    for (int j = 0; j < 6; ++j) acc[j] = (f32x4){0.f,0.f,0.f,0.f};

    const int xrow = tid >> 3, xk = (tid & 7) * 8;
    const int wcol = tid >> 1, wk = (tid & 1) * 32;
    const int vcol = tid >> 2, vk = (tid & 3) * 16;

    f32x4   px0, px1;
    ushort8 pw[4], pwv[2];

    {
        const float* xp = &x[(size_t)(r0 + xrow)*CD + xk];
        px0 = *(const f32x4*)xp;  px1 = *(const f32x4*)(xp + 4);
        const ushort_t* hp = &wqk[(size_t)wcol*CD + wk];
        #pragma unroll
        for (int i = 0; i < 4; ++i) pw[i] = *(const ushort8*)(hp + 8*i);
        const ushort_t* vp = &wv_t[(size_t)vcol*CD + vk];
        pwv[0] = *(const ushort8*)vp;  pwv[1] = *(const ushort8*)(vp + 8);
    }

    for (int kt = 0; kt < 8; ++kt) {
        __syncthreads();
        {
            ushort8 h8;
            #pragma unroll
            for (int i = 0; i < 8; ++i)
                h8[i] = f2h((i < 4) ? px0[i] : px1[i-4]);
            *(ushort8*)&xs_s[xrow*72 + xk] = h8;
        }
        #pragma unroll
        for (int i = 0; i < 4; ++i)
            *(ushort8*)&wqk_s[wcol*72 + wk + 8*i] = pw[i];
        *(ushort8*)&wv_s[vcol*72 + vk]     = pwv[0];
        *(ushort8*)&wv_s[vcol*72 + vk + 8] = pwv[1];

        if (kt + 1 < 8) {
            const int ko = (kt + 1) * 64;
            const float* xp = &x[(size_t)(r0 + xrow)*CD + ko + xk];
            px0 = *(const f32x4*)xp;  px1 = *(const f32x4*)(xp + 4);
            const ushort_t* hp = &wqk[(size_t)wcol*CD + ko + wk];
            #pragma unroll
            for (int i = 0; i < 4; ++i) pw[i] = *(const ushort8*)(hp + 8*i);
            const ushort_t* vp = &wv_t[(size_t)vcol*CD + ko + vk];
            pwv[0] = *(const ushort8*)vp;  pwv[1] = *(const ushort8*)(vp + 8);
        }
        __syncthreads();

        #pragma unroll
        for (int k32 = 0; k32 < 2; ++k32) {
            const int ao = (rf*16 + l15)*72 + 8*l4 + 32*k32;
            half8 ax = *(const half8*)&xs_s[ao];
            #pragma unroll
            for (int j = 0; j < 6; ++j) {
                const int cf = 6*cg + j;
                if (cf < 8) {
                    const int bo = (16*cf + l15)*72 + 8*l4 + 32*k32;
                    half8 bw = *(const half8*)&wqk_s[bo];
                    acc[j] = MFMAH(ax, bw, acc[j]);
                } else {
                    const int bo = ((cf-8)*16 + l15)*72 + 8*l4 + 32*k32;
                    half8 bw = *(const half8*)&wv_s[bo];
                    acc[j] = MFMAH(ax, bw, acc[j]);
                }
            }
        }
    }

    #pragma unroll
    for (int j = 0; j < 6; ++j) {
        const int cf = 6*cg + j;
        const int col16 = cf*16 + l15;
        if (cf < 4) {
            const float bias = bq[col16] * LOG2E;
            #pragma unroll
            for (int r = 0; r < 4; ++r) {
                const size_t row = (size_t)(r0 + rf*16 + 4*l4 + r);
                qf[row*DD + col16] = f2h(fmaxf(acc[j][r] + bias, 0.f));
            }
        } else if (cf < 8) {
            const int kc = col16 - 64;
            const float bias = bk[kc];
            #pragma unroll
            for (int r = 0; r < 4; ++r) {
                const size_t row = (size_t)(r0 + rf*16 + 4*l4 + r);
                kf[row*DD + kc] = f2h(fmaxf(acc[j][r] + bias, 0.f));
            }
        } else {
            const int d = col16 - 128;
            const float bias = bv[d];
            #pragma unroll
            for (int r = 0; r < 4; ++r)
                vtile[d*40 + rf*16 + 4*l4 + r] =
                    f2bf(fmaxf(acc[j][r] + bias, 0.f));
        }
    }
    __syncthreads();
    {
        const int d  = tid >> 2;
        const int j8 = (tid & 3) * 8;
        const int bb   = r0 / NTOK;
        const int tok0 = r0 % NTOK;
        ushort8 vv = *(const ushort8*)&vtile[d*40 + j8];
        *(ushort8*)&vT[((size_t)bb*DD + d)*NTOK + tok0 + j8] = vv;
    }
}

// ---------------------------------------------------------------------------
// Kernel 2: flash attention. QK^T in fp16 (single MFMA, 2^-11 precision);
// P/V in bf16 (range for no-max exp2 P up to 2^43). Structure = r11:
// BQ=256, 8 waves, split-K, XCD-pinned seg = bid % nseg, early prefetch.
// ---------------------------------------------------------------------------
__global__ __launch_bounds__(512, 4) void attn_kernel(
    const ushort_t* __restrict__ qf, const ushort_t* __restrict__ kf,
    const ushort_t* __restrict__ vT,
    float* __restrict__ o_part, float* __restrict__ l_part, int nseg)
{
    __shared__ __align__(16) ushort_t kf_s[BK*KSTR];   // fp16 [key][d]
    __shared__ __align__(16) ushort_t vt_s[DD*KSTR];   // bf16 [d][key]
    __shared__ __align__(16) ushort_t p_s [BQ*PSTR];   // bf16, wave-private

    const int tid  = threadIdx.x;
    const int w    = tid >> 6;     // 0..7
    const int lane = tid & 63;
    const int l15  = lane & 15;
    const int l4   = lane >> 4;

    const int p    = blockIdx.x;
    const int seg  = p % nseg;           // at nseg==8: seg pins to one XCD
    const int rest = p / nseg;
    const int qb   = rest & (NTOK/BQ - 1);
    const int b    = rest / (NTOK/BQ);
    const int kv0  = seg * (NTOK / nseg);
    const int tiles = (NTOK / nseg) / BK;

    // Q fragments (fp16): 2 row-frags (u) x 2 k-slices (s)
    half8 qfr[2][2];
    #pragma unroll
    for (int u = 0; u < 2; ++u) {
        const size_t qrow = ((size_t)b*NTOK + (size_t)qb*BQ + 32*w + 16*u + l15)*DD;
        #pragma unroll
        for (int s = 0; s < 2; ++s)
            qfr[u][s] = *(const half8*)&qf[qrow + 8*l4 + 32*s];
    }

    f32x4 acc[2][4];
    float l_run[2][4];
    #pragma unroll
    for (int u = 0; u < 2; ++u)
        #pragma unroll
        for (int nt = 0; nt < 4; ++nt) {
            acc[u][nt] = (f32x4){0.f,0.f,0.f,0.f};
            l_run[u][nt] = 0.f;
        }

    // staging: 512 thr; K covers 64x64 fp16 with 8 thr/row; V same bf16
    const int skey = tid >> 3;          // 0..63
    const int sc   = (tid & 7) * 8;
    ushort8 rgk, rgv;
    {
        rgk = *(const ushort8*)&kf[((size_t)b*NTOK + kv0 + skey)*DD + sc];
        rgv = *(const ushort8*)&vT[((size_t)b*DD + skey)*NTOK + kv0 + sc];
    }

    for (int t = 0; t < tiles; ++t) {
        __syncthreads();
        *(ushort8*)&kf_s[skey*KSTR + sc] = rgk;
        *(ushort8*)&vt_s[skey*KSTR + sc] = rgv;
        if (t + 1 < tiles) {  // prefetch now: full compute phase of cover
            rgk = *(const ushort8*)&kf[((size_t)b*NTOK + kv0 + (t+1)*BK + skey)*DD + sc];
            rgv = *(const ushort8*)&vT[((size_t)b*DD + skey)*NTOK + kv0 + (t+1)*BK + sc];
        }
        __syncthreads();

        // ---- S (log2 domain) = Q K^T, fp16 single MFMA ----
        f32x4 sv[2][4];
        #pragma unroll
        for (int u = 0; u < 2; ++u)
            #pragma unroll
            for (int nt = 0; nt < 4; ++nt) sv[u][nt] = (f32x4){0.f,0.f,0.f,0.f};
        #pragma unroll
        for (int s = 0; s < 2; ++s)
            #pragma unroll
            for (int nt = 0; nt < 4; ++nt) {
                half8 kfr = *(const half8*)&kf_s[(16*nt + l15)*KSTR + 8*l4 + 32*s];
                #pragma unroll
                for (int u = 0; u < 2; ++u)
                    sv[u][nt] = MFMAH(qfr[u][s], kfr, sv[u][nt]);
            }

        // ---- no-max softmax: P = exp2(S); deferred row-sum ----
        #pragma unroll
        for (int u = 0; u < 2; ++u)
            #pragma unroll
            for (int r = 0; r < 4; ++r) {
                float s0 = EXP2(sv[u][0][r]);
                float s1 = EXP2(sv[u][1][r]);
                float s2 = EXP2(sv[u][2][r]);
                float s3 = EXP2(sv[u][3][r]);
                sv[u][0][r] = s0; sv[u][1][r] = s1;
                sv[u][2][r] = s2; sv[u][3][r] = s3;
                l_run[u][r] += (s0 + s1) + (s2 + s3);
            }

        // ---- P -> LDS (bf16: range up to 2^43), wave-private rows ----
        #pragma unroll
        for (int u = 0; u < 2; ++u)
            #pragma unroll
            for (int nt = 0; nt < 4; ++nt)
                #pragma unroll
                for (int r = 0; r < 4; ++r)
                    p_s[(32*w + 16*u + 4*l4 + r)*PSTR + 16*nt + l15] =
                        f2bf(sv[u][nt][r]);

        // ---- PV (bf16): V-frags shared across both u ----
        bf16x8 paf[2][2];
        #pragma unroll
        for (int u = 0; u < 2; ++u)
            #pragma unroll
            for (int s = 0; s < 2; ++s)
                paf[u][s] = *(const bf16x8*)&p_s[(32*w + 16*u + l15)*PSTR + 8*l4 + 32*s];
        #pragma unroll
        for (int s = 0; s < 2; ++s)
            #pragma unroll
            for (int nt = 0; nt < 4; ++nt) {
                bf16x8 vf = *(const bf16x8*)&vt_s[(16*nt + l15)*KSTR + 8*l4 + 32*s];
                #pragma unroll
                for (int u = 0; u < 2; ++u)
                    acc[u][nt] = MFMAB(paf[u][s], vf, acc[u][nt]);
            }
    }

    // epilogue: one butterfly row-sum, write unnormalized partials + l
    const size_t prow0 = (size_t)(seg*4 + b)*NTOK + (size_t)qb*BQ + 32*w;
    #pragma unroll
    for (int u = 0; u < 2; ++u)
        #pragma unroll
        for (int r = 0; r < 4; ++r) {
            float ls = l_run[u][r];
            ls += __shfl_xor(ls, 1);
            ls += __shfl_xor(ls, 2);
            ls += __shfl_xor(ls, 4);
            ls += __shfl_xor(ls, 8);
            const size_t row = prow0 + 16*u + 4*l4 + r;
            #pragma unroll
            for (int nt = 0; nt < 4; ++nt)
                o_part[row*DD + 16*nt + l15] = acc[u][nt][r];
            if (l15 == 0) l_part[row] = ls;
        }
}

// ---------------------------------------------------------------------------
// Kernel 3: output projection fp16 MFMA GEMM with fused split-K combine.
// ---------------------------------------------------------------------------
__global__ __launch_bounds__(256) void oproj_gemm(
    const float* __restrict__ o_part, const float* __restrict__ l_part,
    const ushort_t* __restrict__ woT, const float* __restrict__ bo,
    float* __restrict__ out, int nseg)
{
    const int tid  = threadIdx.x;
    const int w    = tid >> 6;
    const int lane = tid & 63;
    const int l15  = lane & 15;
    const int l4   = lane >> 4;
    const int r0   = blockIdx.x * 32;
    const int rf   = w & 1;
    const int cg   = w >> 1;

    const int row = r0 + rf*16 + l15;
    float lsum = 0.f;
    for (int s = 0; s < nseg; ++s)
        lsum += l_part[(size_t)s*NROWS + row];
    const float inv = 1.0f / lsum;

    f32x4 acc[16];
    #pragma unroll
    for (int j = 0; j < 16; ++j) acc[j] = (f32x4){0.f,0.f,0.f,0.f};

    #pragma unroll
    for (int ks = 0; ks < 2; ++ks) {
        const int k0 = 8*l4 + 32*ks;
        float ov[8] = {0.f,0.f,0.f,0.f,0.f,0.f,0.f,0.f};
        for (int s = 0; s < nseg; ++s) {
            const float* op = &o_part[((size_t)s*NROWS + row)*DD + k0];
            const f32x4 a0 = *(const f32x4*)op;
            const f32x4 a1 = *(const f32x4*)(op + 4);
            #pragma unroll
            for (int i = 0; i < 4; ++i) {
                ov[i]   += a0[i];
                ov[i+4] += a1[i];
            }
        }
        half8 ah;
        #pragma unroll
        for (int i = 0; i < 8; ++i)
            ah[i] = (_Float16)(ov[i] * inv);
        #pragma unroll
        for (int j = 0; j < 16; ++j) {
            const int cf = cg*16 + j;
            const half8 bfr = *(const half8*)&woT[(size_t)(16*cf + l15)*DD + k0];
            acc[j] = MFMAH(ah, bfr, acc[j]);
        }
    }

    #pragma unroll
    for (int j = 0; j < 16; ++j) {
        const int col  = (cg*16 + j)*16 + l15;
        const float bias = bo[col];
        #pragma unroll
        for (int r = 0; r < 4; ++r)
            out[(size_t)(r0 + rf*16 + 4*l4 + r)*CD + col] =
                fmaxf(acc[j][r] + bias, 0.f);
    }
}

// ---------------------------------------------------------------------------
extern "C" void kernel_launch(void* const* d_in, const int* in_sizes, int n_in,
                              void* d_out, int out_size, void* d_ws, size_t ws_size,
                              hipStream_t stream) {
    const float* x  = (const float*)d_in[0];
    const float* Wq = (const float*)d_in[1];
    const float* bq = (const float*)d_in[2];
    const float* Wk = (const float*)d_in[3];
    const float* bk = (const float*)d_in[4];
    const float* Wv = (const float*)d_in[5];
    const float* bv = (const float*)d_in[6];
    const float* Wo = (const float*)d_in[7];
    const float* bo = (const float*)d_in[8];
    float* out = (float*)d_out;

    ushort_t* u = (ushort_t*)d_ws;
    const size_t SEG = (size_t)NROWS * DD;  // 1048576 elems
    ushort_t* qf  = u;                      // fp16
    ushort_t* kf  = u + SEG;                // fp16
    ushort_t* vT  = u + 2*SEG;              // bf16

    ushort_t* wqk  = u + 3*SEG;             // 128*512 fp16
    ushort_t* wv_t = wqk + 128*512;         // 64*512 fp16
    ushort_t* woT  = wv_t + 64*512;         // 512*64 fp16
    float*    o_part = (float*)(woT + 512*64);

    const size_t base_b  = (3*SEG + 192*512 + 512*64) * sizeof(ushort_t);
    const size_t per_seg = (size_t)NROWS*DD*4 + (size_t)NROWS*4;  // 4MB+64KB
    int nseg = 1;
    if      (ws_size >= base_b + 8*per_seg) nseg = 8;
    else if (ws_size >= base_b + 4*per_seg) nseg = 4;
    else if (ws_size >= base_b + 2*per_seg) nseg = 2;
    float* l_part = o_part + (size_t)nseg*NROWS*DD;

    wprep_kernel<<<512, 256, 0, stream>>>(Wq, Wk, Wv, Wo, wqk, wv_t, woT);
    qkv_gemm<<<NROWS/32, 256, 0, stream>>>(x, wqk, wv_t,
                                           bq, bk, bv, qf, kf, vT);
    attn_kernel<<<(NTOK/BQ) * 4 * nseg, 512, 0, stream>>>(
        qf, kf, vT, o_part, l_part, nseg);
    oproj_gemm<<<NROWS/32, 256, 0, stream>>>(o_part, l_part, woT,
                                             bo, out, nseg);
}